// Round 11
// baseline (1994.642 us; speedup 1.0000x reference)
//
#include <hip/hip_runtime.h>
#include <cmath>

#define HID 51
#define BATCH 256
#define BLK 768       // 3 layer-sections x 256 (12 waves, 3/SIMD)
#define OUT_TID 716   // layer-2 section, wave 11, lane 12 (unit 51 slot = idle)

typedef _Float16 half2_t __attribute__((ext_vector_type(2)));

// r8 structure (PASSED, 1979us, absmax 1.22e-4) + r9's register pin.
// One block per batch element. tid = layer*256 + unit*4 + gt (unit<51 valid).
// Each gate thread: wA = Wih row (vs h_{layer-1}), wB = Whh row (vs h_layer),
// packed fp16 (2 x 26 half2 VGPRs). Layer0: wA = Whh1 row, wx = Wih1, no wB.
// amdgpu_waves_per_eu(4,4) pins the arch-VGPR budget to 128 so all 52 weight
// regs stay ARCH-resident (r8's measured VGPR_Count=40 proved they were
// AGPR-shuffled -> ~150 copies/wave/tick; r9 proved the pin fixes this).
// h broadcast via readlane: each lane ds_read_b32 ONE h pair (lanes 0..31 =
// row selA, 32..63 = row selB), then 26 x {readlane, v_dot2_f32_f16} per row.
// Double-buffered h (read hb[tau&1], write hb[tau&1^1]) -> ONE barrier/tick.
// Gate quad gathered into gt==0 lane via 3 ds_swizzle; cell update in-wave
// (c_state in register). Output thread OUT_TID: wA=0, wB=Wl, t_off=3; obuf
// ring flushed 64-wide by wave 3 every 64 ticks.

__device__ __forceinline__ float fsig(float v) {
    return __builtin_amdgcn_rcpf(1.f + __expf(-v));
}
__device__ __forceinline__ float ftanh(float v) {
    const float e = __expf(2.f * v);                 // inf-safe
    return fmaf(-2.f, __builtin_amdgcn_rcpf(e + 1.f), 1.f);
}
__device__ __forceinline__ half2_t h2bits(int b) {
    union { int i; half2_t h; } u; u.i = b; return u.h;
}

__attribute__((amdgpu_waves_per_eu(4, 4)))
__global__ __launch_bounds__(BLK)
void lstm3_kernel(const float* __restrict__ x,
                  const float* __restrict__ Wih1, const float* __restrict__ Whh1,
                  const float* __restrict__ bih1, const float* __restrict__ bhh1,
                  const float* __restrict__ Wih,  const float* __restrict__ Whh,
                  const float* __restrict__ bih,  const float* __restrict__ bhh,
                  const float* __restrict__ Wl,   const float* __restrict__ bl,
                  float* __restrict__ out, int T)
{
    const int b     = blockIdx.x;
    const int tid   = threadIdx.x;
    const int layer = tid >> 8;        // 0..2, wave-uniform (4 waves/section)
    const int sub   = tid & 255;
    const int unit  = sub >> 2;        // 0..63 (valid < 51)
    const int gt    = sub & 3;         // 0=i 1=f 2=g 3=o
    const int lane  = tid & 63;

    __shared__ __align__(16) float    xbuf[2048];
    __shared__ __align__(16) _Float16 hb[2][3][64];   // dbuf h rows, 128 B each
    __shared__ __align__(16) float    obuf[128];      // output ring (2 x 64)

    for (int i = tid; i < T; i += BLK) xbuf[i] = x[(size_t)b * T + i];
    if (tid < 192) ((float*)hb)[tid] = 0.f;           // zero both h buffers

    // ---------------- role setup ----------------
    const bool role_out = (tid == OUT_TID);
    const bool is_gate  = (unit < HID);
    const bool is_cell  = is_gate && (gt == 0);

    const float* rowA = nullptr;
    const float* rowB = nullptr;
    float wx = 0.f, bias = 0.f;
    const int selA = (layer == 0) ? 0 : layer - 1;    // section-uniform
    const int selB = layer;
    int t_off = layer;
    if (is_gate) {
        const int r = gt * HID + unit;                // PyTorch gate-row index
        if (layer == 0) {
            wx   = Wih1[r];
            bias = bih1[r] + bhh1[r];
            rowA = Whh1 + (size_t)r * 51;             // vs h0 (selA=0)
        } else {
            const int gr = (layer - 1) * 204 + r;
            bias = bih[gr] + bhh[gr];
            rowA = Wih + (size_t)gr * 51;             // vs h_{layer-1}
            rowB = Whh + (size_t)gr * 51;             // vs h_layer
        }
    } else if (role_out) {
        bias = bl[0];
        rowB = Wl;                                    // out = bl + Wl.h2 (selB=2)
        t_off = 3;
    }

    half2_t wA[26], wB[26];
    #pragma unroll
    for (int j = 0; j < 26; ++j) {
        wA[j] = half2_t{(_Float16)0.f, (_Float16)0.f};
        wB[j] = half2_t{(_Float16)0.f, (_Float16)0.f};
    }
    if (rowA) {
        #pragma unroll
        for (int j = 0; j < 25; ++j)
            wA[j] = half2_t{(_Float16)rowA[2*j], (_Float16)rowA[2*j+1]};
        wA[25] = half2_t{(_Float16)rowA[50], (_Float16)0.f};
    }
    if (rowB) {
        #pragma unroll
        for (int j = 0; j < 25; ++j)
            wB[j] = half2_t{(_Float16)rowB[2*j], (_Float16)rowB[2*j+1]};
        wB[25] = half2_t{(_Float16)rowB[50], (_Float16)0.f};
    }

    float c_state = 0.f;
    __syncthreads();

    const int TICKS = T + 4;                          // +4 so the last flush runs
    for (int tau = 0; tau < TICKS; ++tau) {
        const int par = tau & 1;
        const int  t    = tau - t_off;                // per-lane (out lane differs)
        const bool pred = (unsigned)t < (unsigned)T;

        // ---- one ds_read_b32 per lane: own h pair (2-way bank alias = free) ----
        const int psel = (lane < 32) ? selA : selB;
        const int hpx  = *(const int*)((const char*)(&hb[par][0][0])
                                       + psel * 128 + (lane & 31) * 4);

        // ---- dots via readlane broadcast (VALU pipe, not LDS pipe) ----
        float acc0 = bias, acc1 = 0.f, acc2 = 0.f, acc3 = 0.f;
        if (layer == 0) {                             // wave-uniform branch
            acc0 = fmaf(wx, xbuf[pred ? t : 0], bias);
            #pragma unroll
            for (int j = 0; j < 26; ++j) {
                const half2_t a = h2bits(__builtin_amdgcn_readlane(hpx, j));
                if (j & 1) acc1 = __builtin_amdgcn_fdot2(wA[j], a, acc1, false);
                else       acc0 = __builtin_amdgcn_fdot2(wA[j], a, acc0, false);
            }
        } else {
            #pragma unroll
            for (int j = 0; j < 26; ++j) {
                const half2_t a = h2bits(__builtin_amdgcn_readlane(hpx, j));
                const half2_t v = h2bits(__builtin_amdgcn_readlane(hpx, 32 + j));
                if (j & 1) { acc1 = __builtin_amdgcn_fdot2(wA[j], a, acc1, false);
                             acc3 = __builtin_amdgcn_fdot2(wB[j], v, acc3, false); }
                else       { acc0 = __builtin_amdgcn_fdot2(wA[j], a, acc0, false);
                             acc2 = __builtin_amdgcn_fdot2(wB[j], v, acc2, false); }
            }
        }
        const float acc = (acc0 + acc1) + (acc2 + acc3);

        // ---- quad gather: lane 4u+0 collects i,f,g,o ----
        const float fpre = __int_as_float(__builtin_amdgcn_ds_swizzle(__float_as_int(acc),  0x041F));
        const float gpre = __int_as_float(__builtin_amdgcn_ds_swizzle(__float_as_int(acc),  0x081F));
        const float opre = __int_as_float(__builtin_amdgcn_ds_swizzle(__float_as_int(fpre), 0x081F));

        if (pred) {
            if (is_cell) {
                const float si = fsig(acc);
                const float sf = fsig(fpre);
                const float tg = ftanh(gpre);
                const float so = fsig(opre);
                const float c  = fmaf(sf, c_state, si * tg);
                c_state = c;
                hb[par ^ 1][layer][unit] = (_Float16)(so * ftanh(c));
            } else if (role_out) {
                obuf[t & 127] = acc;                  // t = tau-3
            }
        }
        // ---- coalesced flush: slots read were written before last barrier ----
        if ((tid >> 6) == 3 && (tau & 63) == 3 && tau >= 67) {
            const int t0 = tau - 67;                  // multiple of 64
            out[(size_t)b * T + t0 + lane] = obuf[(t0 & 64) + lane];
        }
        __syncthreads();
    }
}

extern "C" void kernel_launch(void* const* d_in, const int* in_sizes, int n_in,
                              void* d_out, int out_size, void* d_ws, size_t ws_size,
                              hipStream_t stream) {
    const float* x    = (const float*)d_in[0];
    const float* Wih1 = (const float*)d_in[1];
    const float* Whh1 = (const float*)d_in[2];
    const float* bih1 = (const float*)d_in[3];
    const float* bhh1 = (const float*)d_in[4];
    const float* Wih  = (const float*)d_in[5];
    const float* Whh  = (const float*)d_in[6];
    const float* bih  = (const float*)d_in[7];
    const float* bhh  = (const float*)d_in[8];
    const float* Wl   = (const float*)d_in[9];
    const float* bl   = (const float*)d_in[10];
    float* out = (float*)d_out;

    const int T = in_sizes[0] / BATCH;   // 2048 (flush assumes T % 64 == 0)
    lstm3_kernel<<<BATCH, BLK, 0, stream>>>(x, Wih1, Whh1, bih1, bhh1,
                                            Wih, Whh, bih, bhh, Wl, bl, out, T);
}